// Round 4
// baseline (136.339 us; speedup 1.0000x reference)
//
#include <hip/hip_runtime.h>
#include <math.h>

#define FT 48
#define NPIX 2304
#define CIN 24
#define HC 96
#define NORM_SCALE 0.007843137718737125f
#define OUT_SCALE 0.02083333395421505f
#define DELTA 1.8f
#define NPROD 144            // producer blocks: 72 hm_hp + 72 hm
#define NDEC 17              // last 17 tickets decode keypoints

struct PF {
    const float* x;
    const float* w[4][6];    // head 0=hm_hp, 1=hm, 2=hps, 3=hp_offset
                             // per head: dw_w, dw_b, pw1_w, pw1_b, pw2_w, pw2_b
    float* hmhp_sig;         // [17][2304]
    float* pval;             // [72]
    int*   pidx;             // [72]
    int*   counter;          // [1], zeroed by memset node
    float* out;              // [51]
};

__device__ __forceinline__ float sigmoidf_(float v) { return 1.0f / (1.0f + expf(-v)); }

__device__ __forceinline__ float dw_tap(const float* __restrict__ x,
                                        const float* __restrict__ dw_w,
                                        const float* __restrict__ dw_b,
                                        int ci, int pixel)
{
    const int py = pixel / FT, px = pixel % FT;
    float acc = dw_b[ci];
#pragma unroll
    for (int ky = 0; ky < 3; ++ky) {
        const int yy = py + ky - 1;
#pragma unroll
        for (int kx = 0; kx < 3; ++kx) {
            const int xx = px + kx - 1;
            float v = 0.0f;
            if (yy >= 0 && yy < FT && xx >= 0 && xx < FT)
                v = x[ci * NPIX + yy * FT + xx] * NORM_SCALE - 1.0f;
            acc = fmaf(dw_w[ci * 9 + ky * 3 + kx], v, acc);
        }
    }
    return acc;
}

__global__ __launch_bounds__(256) void fused(PF p)
{
    // ---- producer weight staging ----
    __shared__ float s_dww[216];
    __shared__ float s_dwb[24];
    __shared__ float s_pw1w[HC * CIN];    // [co][ci]
    __shared__ float s_pw1b[HC];
    __shared__ float s_pw2t[HC * 17];     // hm_hp: [co][k]; hm: [co] in first 96
    __shared__ float s_pw2b[17];
    __shared__ float sv[4];
    __shared__ int si[4];
    __shared__ int s_ticket;
    // ---- decode scratch ----
    __shared__ float s_red[256];
    __shared__ int s_redi[256];
    __shared__ float s_dwv[CIN];
    __shared__ float sA[HC];
    __shared__ float s_ky, s_kx;
    __shared__ int s_ct, s_top;

    const int t = threadIdx.x;
    const int b = blockIdx.x;
    const bool is_hm = (b >= 72);
    const int lb = is_hm ? b - 72 : b;
    const int head = is_hm ? 1 : 0;

    const float* dw_w  = p.w[head][0];
    const float* dw_b  = p.w[head][1];
    const float* pw1_w = p.w[head][2];
    const float* pw1_b = p.w[head][3];
    const float* pw2_w = p.w[head][4];
    const float* pw2_b = p.w[head][5];

    // stage weights -> LDS
    if (t < 216) s_dww[t] = dw_w[t];
    if (t < 24) s_dwb[t] = dw_b[t];
    for (int i = t; i < HC * CIN; i += 256) s_pw1w[i] = pw1_w[i];
    if (t < HC) s_pw1b[t] = pw1_b[t];
    if (!is_hm) {
        for (int i = t; i < HC * 17; i += 256) {
            const int co = i / 17, k = i - co * 17;
            s_pw2t[i] = pw2_w[k * HC + co];
        }
        if (t < 17) s_pw2b[t] = pw2_b[t];
    } else {
        if (t < HC) s_pw2t[t] = pw2_w[t];
        if (t == 0) s_pw2b[0] = pw2_b[0];
    }
    __syncthreads();

    // ---- producer compute: 32 pixels/block, 8 lanes cooperate per pixel ----
    const int lane = t & 63;
    const int split = lane & 7;
    const int pix = lb * 32 + (t >> 3);
    const int py = pix / FT;
    const int px = pix % FT;

    // depthwise: lane computes dw channels 3*split..3*split+2
    float part[3];
#pragma unroll
    for (int c = 0; c < 3; ++c) {
        const int ci = split * 3 + c;
        float acc = s_dwb[ci];
#pragma unroll
        for (int ky = 0; ky < 3; ++ky) {
            const int yy = py + ky - 1;
#pragma unroll
            for (int kx = 0; kx < 3; ++kx) {
                const int xx = px + kx - 1;
                float v = 0.0f;
                if (yy >= 0 && yy < FT && xx >= 0 && xx < FT)
                    v = p.x[ci * NPIX + yy * FT + xx] * NORM_SCALE - 1.0f;
                acc = fmaf(s_dww[ci * 9 + ky * 3 + kx], v, acc);
            }
        }
        part[c] = acc;
    }

    // share dwv[24] within the 8-lane group
    float dwv[CIN];
    const int gbase = lane & ~7;
#pragma unroll
    for (int ci = 0; ci < CIN; ++ci) {
        const float v = (ci % 3 == 0) ? part[0] : ((ci % 3 == 1) ? part[1] : part[2]);
        dwv[ci] = __shfl(v, gbase | (ci / 3), 64);
    }

    if (!is_hm) {
        float oacc[17];
#pragma unroll
        for (int k = 0; k < 17; ++k) oacc[k] = 0.0f;
#pragma unroll 4
        for (int j = 0; j < 12; ++j) {
            const int co = j * 8 + split;
            float a = s_pw1b[co];
#pragma unroll
            for (int ci = 0; ci < CIN; ++ci)
                a = fmaf(s_pw1w[co * CIN + ci], dwv[ci], a);
            a = fmaxf(a, 0.0f);
#pragma unroll
            for (int k = 0; k < 17; ++k)
                oacc[k] = fmaf(s_pw2t[co * 17 + k], a, oacc[k]);
        }
#pragma unroll
        for (int off = 1; off < 8; off <<= 1)
#pragma unroll
            for (int k = 0; k < 17; ++k)
                oacc[k] += __shfl_xor(oacc[k], off, 64);
        {
            int k = split;
            p.hmhp_sig[k * NPIX + pix] = sigmoidf_(oacc[k] + s_pw2b[k]);
            k = split + 8;
            p.hmhp_sig[k * NPIX + pix] = sigmoidf_(oacc[k] + s_pw2b[k]);
            if (split == 0)
                p.hmhp_sig[16 * NPIX + pix] = sigmoidf_(oacc[16] + s_pw2b[16]);
        }
    } else {
        float acc1 = 0.0f;
#pragma unroll 4
        for (int j = 0; j < 12; ++j) {
            const int co = j * 8 + split;
            float a = s_pw1b[co];
#pragma unroll
            for (int ci = 0; ci < CIN; ++ci)
                a = fmaf(s_pw1w[co * CIN + ci], dwv[ci], a);
            a = fmaxf(a, 0.0f);
            acc1 = fmaf(s_pw2t[co], a, acc1);
        }
#pragma unroll
        for (int off = 1; off < 8; off <<= 1)
            acc1 += __shfl_xor(acc1, off, 64);

        float v = -1e30f;
        int idx = pix;
        if (split == 0) {
            const float o = acc1 + s_pw2b[0];
            const float gy = (float)py - 24.0f, gx = (float)px - 24.0f;
            const float w = 1.0f / (sqrtf(gy * gy + gx * gx) + DELTA);
            v = sigmoidf_(o) * w;
        }
#pragma unroll
        for (int off = 1; off < 64; off <<= 1) {
            const float v2 = __shfl_xor(v, off, 64);
            const int i2 = __shfl_xor(idx, off, 64);
            if (v2 > v || (v2 == v && i2 < idx)) { v = v2; idx = i2; }
        }
        if (lane == 0) { sv[t >> 6] = v; si[t >> 6] = idx; }
        __syncthreads();
        if (t == 0) {
            float bv = sv[0]; int bi = si[0];
#pragma unroll
            for (int w2 = 1; w2 < 4; ++w2)
                if (sv[w2] > bv || (sv[w2] == bv && si[w2] < bi)) { bv = sv[w2]; bi = si[w2]; }
            p.pval[lb] = bv;
            p.pidx[lb] = bi;
        }
    }

    // ---- release + ticket ----
    __syncthreads();
    if (t == 0) {
        __threadfence();
        s_ticket = atomicAdd(p.counter, 1);
    }
    __syncthreads();
    const int ticket = s_ticket;
    if (ticket < NPROD - NDEC) return;
    const int k = ticket - (NPROD - NDEC);   // 0..16

    // ---- acquire: wait for all producers ----
    if (t == 0) {
        while (__hip_atomic_load(p.counter, __ATOMIC_ACQUIRE, __HIP_MEMORY_SCOPE_AGENT) < NPROD)
            __builtin_amdgcn_s_sleep(2);
    }
    __syncthreads();
    __threadfence();

    // ---- finalize center argmax from 72 partials ----
    if (t < 128) {
        float v = -1e30f;
        int i = 0x7fffffff;
        if (t < 72) { v = p.pval[t]; i = p.pidx[t]; }
        s_red[t] = v;
        s_redi[t] = i;
    }
    __syncthreads();
    for (int s = 64; s > 0; s >>= 1) {
        if (t < s) {
            const float v2 = s_red[t + s];
            const int i2 = s_redi[t + s];
            if (v2 > s_red[t] || (v2 == s_red[t] && i2 < s_redi[t])) {
                s_red[t] = v2;
                s_redi[t] = i2;
            }
        }
        __syncthreads();
    }
    if (t == 0) s_ct = s_redi[0];
    __syncthreads();
    const int ct = s_ct;
    const float cty = (float)(ct / FT);
    const float ctx = (float)(ct % FT);

    // ---- hps @ ct ----
    if (t < CIN) s_dwv[t] = dw_tap(p.x, p.w[2][0], p.w[2][1], t, ct);
    __syncthreads();
    if (t < HC) {
        float a = p.w[2][3][t];
#pragma unroll
        for (int ci = 0; ci < CIN; ++ci)
            a = fmaf(p.w[2][2][t * CIN + ci], s_dwv[ci], a);
        sA[t] = fmaxf(a, 0.0f);
    }
    __syncthreads();
    if (t < 64) {
        float vy = 0.0f, vx = 0.0f;
        for (int co = t; co < HC; co += 64) {
            const float av = sA[co];
            vy = fmaf(p.w[2][4][(2 * k) * HC + co], av, vy);
            vx = fmaf(p.w[2][4][(2 * k + 1) * HC + co], av, vx);
        }
#pragma unroll
        for (int off = 1; off < 64; off <<= 1) {
            vy += __shfl_xor(vy, off, 64);
            vx += __shfl_xor(vx, off, 64);
        }
        if (t == 0) {
            s_ky = vy + p.w[2][5][2 * k] + cty;
            s_kx = vx + p.w[2][5][2 * k + 1] + ctx;
        }
    }
    __syncthreads();
    const float kcy = s_ky, kcx = s_kx;

    // ---- distance-weighted argmax over hmhp_sig[k] ----
    float best = -1e30f;
    int bi = 0x7fffffff;
    for (int i = t; i < NPIX; i += 256) {
        const int y = i / FT, xx = i % FT;
        const float dy = (float)y - kcy, dx = (float)xx - kcx;
        const float d = sqrtf(dy * dy + dx * dx) + DELTA;
        const float v = p.hmhp_sig[k * NPIX + i] / d;
        if (v > best || (v == best && i < bi)) { best = v; bi = i; }
    }
    s_red[t] = best;
    s_redi[t] = bi;
    __syncthreads();
    for (int s = 128; s > 0; s >>= 1) {
        if (t < s) {
            const float v2 = s_red[t + s];
            const int i2 = s_redi[t + s];
            if (v2 > s_red[t] || (v2 == s_red[t] && i2 < s_redi[t])) {
                s_red[t] = v2;
                s_redi[t] = i2;
            }
        }
        __syncthreads();
    }
    if (t == 0) s_top = s_redi[0];
    __syncthreads();
    const int top = s_top;

    // ---- hp_offset @ top ----
    if (t < CIN) s_dwv[t] = dw_tap(p.x, p.w[3][0], p.w[3][1], t, top);
    __syncthreads();
    if (t < HC) {
        float a = p.w[3][3][t];
#pragma unroll
        for (int ci = 0; ci < CIN; ++ci)
            a = fmaf(p.w[3][2][t * CIN + ci], s_dwv[ci], a);
        sA[t] = fmaxf(a, 0.0f);
    }
    __syncthreads();
    if (t < 64) {
        float oy = 0.0f, ox = 0.0f;
        for (int co = t; co < HC; co += 64) {
            const float av = sA[co];
            oy = fmaf(p.w[3][4][(2 * k) * HC + co], av, oy);
            ox = fmaf(p.w[3][4][(2 * k + 1) * HC + co], av, ox);
        }
#pragma unroll
        for (int off = 1; off < 64; off <<= 1) {
            oy += __shfl_xor(oy, off, 64);
            ox += __shfl_xor(ox, off, 64);
        }
        if (t == 0) {
            const float ty = (float)(top / FT), tx = (float)(top % FT);
            p.out[k * 3 + 0] = (oy + p.w[3][5][2 * k] + ty) * OUT_SCALE;
            p.out[k * 3 + 1] = (ox + p.w[3][5][2 * k + 1] + tx) * OUT_SCALE;
            p.out[k * 3 + 2] = p.hmhp_sig[k * NPIX + top];
        }
    }
}

// ---------------- launch ----------------

extern "C" void kernel_launch(void* const* d_in, const int* in_sizes, int n_in,
                              void* d_out, int out_size, void* d_ws, size_t ws_size,
                              hipStream_t stream)
{
    (void)in_sizes; (void)n_in; (void)out_size; (void)ws_size;

    float* ws = (float*)d_ws;
    float* hmhp_sig = ws;                          // 17*2304 floats
    float* pval     = ws + 17 * NPIX;              // 72 floats
    int*   pidx     = (int*)(ws + 17 * NPIX + 72); // 72 ints
    int*   counter  = (int*)(ws + 17 * NPIX + 144);

    PF p;
    p.x = (const float*)d_in[0];
    for (int h = 0; h < 4; ++h)
        for (int j = 0; j < 6; ++j)
            p.w[h][j] = (const float*)d_in[1 + h * 6 + j];
    p.hmhp_sig = hmhp_sig;
    p.pval = pval;
    p.pidx = pidx;
    p.counter = counter;
    p.out = (float*)d_out;

    hipMemsetAsync(counter, 0, sizeof(int), stream);
    fused<<<NPROD, 256, 0, stream>>>(p);
}

// Round 5
// 132.342 us; speedup vs baseline: 1.0302x; 1.0302x over previous
//
#include <hip/hip_runtime.h>
#include <math.h>

#define FT 48
#define NPIX 2304
#define CIN 24
#define HC 96
#define NORM_SCALE 0.007843137718737125f
#define OUT_SCALE 0.02083333395421505f
#define DELTA 1.8f
#define NPROD 144            // producer blocks: 72 hm_hp + 72 hm
#define NDEC 17              // last 17 tickets decode keypoints

// self-resetting sync state (module globals: NOT poisoned by the harness;
// statically 0 at load, reset to 0 by the last decode block of every call)
__device__ int g_counter = 0;
__device__ int g_done = 0;

struct PF {
    const float* x;
    const float* w[4][6];    // head 0=hm_hp, 1=hm, 2=hps, 3=hp_offset
                             // per head: dw_w, dw_b, pw1_w, pw1_b, pw2_w, pw2_b
    float* hmhp_sig;         // [17][2304]
    float* pval;             // [72]
    int*   pidx;             // [72]
    float* out;              // [51]
};

__device__ __forceinline__ float sigmoidf_(float v) { return 1.0f / (1.0f + expf(-v)); }

__global__ __launch_bounds__(256) void fused(PF p)
{
    // ---- producer weight staging ----
    __shared__ float s_dww[216];
    __shared__ float s_dwb[24];
    __shared__ float s_pw1w[HC * CIN];    // [co][ci]
    __shared__ float s_pw1b[HC];
    __shared__ float s_pw2t[HC * 17];     // hm_hp: [co][k]; hm: [co] in first 96
    __shared__ float s_pw2b[17];
    __shared__ float sv[4];
    __shared__ int si[4];
    __shared__ int s_ticket;
    // ---- decode weight staging (prefetched during spin-wait) ----
    __shared__ float s2_dww[2][216];      // 0=hps, 1=hp_offset
    __shared__ float s2_dwb[2][24];
    __shared__ float s2_pw1[2][HC * CIN];
    __shared__ float s2_pw1b[2][HC];
    __shared__ float s2_pw2[2][2 * HC];   // rows 2k and 2k+1
    __shared__ float s2_pw2b[2][2];
    // ---- decode scratch ----
    __shared__ float s_red[256];
    __shared__ int s_redi[256];
    __shared__ float s_dwv[CIN];
    __shared__ float sA[HC];
    __shared__ float s_ky, s_kx;
    __shared__ int s_ct, s_top;

    const int t = threadIdx.x;
    const int b = blockIdx.x;
    const bool is_hm = (b >= 72);
    const int lb = is_hm ? b - 72 : b;
    const int head = is_hm ? 1 : 0;

    const float* dw_w  = p.w[head][0];
    const float* dw_b  = p.w[head][1];
    const float* pw1_w = p.w[head][2];
    const float* pw1_b = p.w[head][3];
    const float* pw2_w = p.w[head][4];
    const float* pw2_b = p.w[head][5];

    // stage producer weights -> LDS (cold HBM; overlapped with x tap loads below)
    if (t < 216) s_dww[t] = dw_w[t];
    if (t < 24) s_dwb[t] = dw_b[t];
    for (int i = t; i < HC * CIN; i += 256) s_pw1w[i] = pw1_w[i];
    if (t < HC) s_pw1b[t] = pw1_b[t];
    if (!is_hm) {
        for (int i = t; i < HC * 17; i += 256) {
            const int co = i / 17, k = i - co * 17;
            s_pw2t[i] = pw2_w[k * HC + co];
        }
        if (t < 17) s_pw2b[t] = pw2_b[t];
    } else {
        if (t < HC) s_pw2t[t] = pw2_w[t];
        if (t == 0) s_pw2b[0] = pw2_b[0];
    }

    // ---- producer: 32 pixels/block, 8 lanes cooperate per pixel ----
    const int lane = t & 63;
    const int split = lane & 7;
    const int pix = lb * 32 + (t >> 3);
    const int py = pix / FT;
    const int px = pix % FT;

    // load + normalize this lane's 27 x-taps into registers BEFORE the barrier
    // so the cold global loads overlap the weight staging drain
    float xt[3][9];
#pragma unroll
    for (int c = 0; c < 3; ++c) {
        const int ci = split * 3 + c;
#pragma unroll
        for (int ky = 0; ky < 3; ++ky) {
            const int yy = py + ky - 1;
#pragma unroll
            for (int kx = 0; kx < 3; ++kx) {
                const int xx = px + kx - 1;
                float v = 0.0f;
                if (yy >= 0 && yy < FT && xx >= 0 && xx < FT)
                    v = p.x[ci * NPIX + yy * FT + xx] * NORM_SCALE - 1.0f;
                xt[c][ky * 3 + kx] = v;
            }
        }
    }
    __syncthreads();

    // depthwise: lane computes dw channels 3*split..3*split+2
    float part[3];
#pragma unroll
    for (int c = 0; c < 3; ++c) {
        const int ci = split * 3 + c;
        float acc = s_dwb[ci];
#pragma unroll
        for (int tap = 0; tap < 9; ++tap)
            acc = fmaf(s_dww[ci * 9 + tap], xt[c][tap], acc);
        part[c] = acc;
    }

    // share dwv[24] within the 8-lane group
    float dwv[CIN];
    const int gbase = lane & ~7;
#pragma unroll
    for (int ci = 0; ci < CIN; ++ci) {
        const float v = (ci % 3 == 0) ? part[0] : ((ci % 3 == 1) ? part[1] : part[2]);
        dwv[ci] = __shfl(v, gbase | (ci / 3), 64);
    }

    if (!is_hm) {
        float oacc[17];
#pragma unroll
        for (int k = 0; k < 17; ++k) oacc[k] = 0.0f;
#pragma unroll 4
        for (int j = 0; j < 12; ++j) {
            const int co = j * 8 + split;
            float a = s_pw1b[co];
#pragma unroll
            for (int ci = 0; ci < CIN; ++ci)
                a = fmaf(s_pw1w[co * CIN + ci], dwv[ci], a);
            a = fmaxf(a, 0.0f);
#pragma unroll
            for (int k = 0; k < 17; ++k)
                oacc[k] = fmaf(s_pw2t[co * 17 + k], a, oacc[k]);
        }
#pragma unroll
        for (int off = 1; off < 8; off <<= 1)
#pragma unroll
            for (int k = 0; k < 17; ++k)
                oacc[k] += __shfl_xor(oacc[k], off, 64);
        {
            int k = split;
            p.hmhp_sig[k * NPIX + pix] = sigmoidf_(oacc[k] + s_pw2b[k]);
            k = split + 8;
            p.hmhp_sig[k * NPIX + pix] = sigmoidf_(oacc[k] + s_pw2b[k]);
            if (split == 0)
                p.hmhp_sig[16 * NPIX + pix] = sigmoidf_(oacc[16] + s_pw2b[16]);
        }
    } else {
        float acc1 = 0.0f;
#pragma unroll 4
        for (int j = 0; j < 12; ++j) {
            const int co = j * 8 + split;
            float a = s_pw1b[co];
#pragma unroll
            for (int ci = 0; ci < CIN; ++ci)
                a = fmaf(s_pw1w[co * CIN + ci], dwv[ci], a);
            a = fmaxf(a, 0.0f);
            acc1 = fmaf(s_pw2t[co], a, acc1);
        }
#pragma unroll
        for (int off = 1; off < 8; off <<= 1)
            acc1 += __shfl_xor(acc1, off, 64);

        float v = -1e30f;
        int idx = pix;
        if (split == 0) {
            const float o = acc1 + s_pw2b[0];
            const float gy = (float)py - 24.0f, gx = (float)px - 24.0f;
            const float w = 1.0f / (sqrtf(gy * gy + gx * gx) + DELTA);
            v = sigmoidf_(o) * w;
        }
#pragma unroll
        for (int off = 1; off < 64; off <<= 1) {
            const float v2 = __shfl_xor(v, off, 64);
            const int i2 = __shfl_xor(idx, off, 64);
            if (v2 > v || (v2 == v && i2 < idx)) { v = v2; idx = i2; }
        }
        if (lane == 0) { sv[t >> 6] = v; si[t >> 6] = idx; }
        __syncthreads();
        if (t == 0) {
            float bv = sv[0]; int bi = si[0];
#pragma unroll
            for (int w2 = 1; w2 < 4; ++w2)
                if (sv[w2] > bv || (sv[w2] == bv && si[w2] < bi)) { bv = sv[w2]; bi = si[w2]; }
            p.pval[lb] = bv;
            p.pidx[lb] = bi;
        }
    }

    // ---- release + ticket ----
    __syncthreads();
    if (t == 0) {
        __threadfence();
        s_ticket = atomicAdd(&g_counter, 1);
    }
    __syncthreads();
    const int ticket = s_ticket;
    if (ticket < NPROD - NDEC) return;
    const int k = ticket - (NPROD - NDEC);   // 0..16

    // ---- prefetch decode weights into LDS while waiting (independent of producers) ----
    for (int i = t; i < HC * CIN; i += 256) {
        s2_pw1[0][i] = p.w[2][2][i];
        s2_pw1[1][i] = p.w[3][2][i];
    }
    if (t < HC) {
        s2_pw1b[0][t] = p.w[2][3][t];
        s2_pw1b[1][t] = p.w[3][3][t];
        s2_pw2[0][t]      = p.w[2][4][(2 * k) * HC + t];
        s2_pw2[0][HC + t] = p.w[2][4][(2 * k + 1) * HC + t];
        s2_pw2[1][t]      = p.w[3][4][(2 * k) * HC + t];
        s2_pw2[1][HC + t] = p.w[3][4][(2 * k + 1) * HC + t];
    }
    if (t < 216) { s2_dww[0][t] = p.w[2][0][t]; s2_dww[1][t] = p.w[3][0][t]; }
    if (t < 24)  { s2_dwb[0][t] = p.w[2][1][t]; s2_dwb[1][t] = p.w[3][1][t]; }
    if (t < 2)   { s2_pw2b[0][t] = p.w[2][5][2 * k + t]; s2_pw2b[1][t] = p.w[3][5][2 * k + t]; }

    // ---- acquire: wait for all producers ----
    if (t == 0) {
        while (__hip_atomic_load(&g_counter, __ATOMIC_ACQUIRE, __HIP_MEMORY_SCOPE_AGENT) < NPROD)
            __builtin_amdgcn_s_sleep(2);
    }
    __syncthreads();
    __threadfence();

    // ---- prefetch this keypoint's heatmap row into registers (consumed later) ----
    float r[9];
#pragma unroll
    for (int j = 0; j < 9; ++j)
        r[j] = p.hmhp_sig[k * NPIX + 256 * j + t];

    // ---- finalize center argmax from 72 partials: single wave-0 butterfly ----
    if (t < 64) {
        float v = p.pval[t];
        int i = p.pidx[t];
        if (t < 8) {
            const float v2 = p.pval[64 + t];
            const int i2 = p.pidx[64 + t];
            if (v2 > v || (v2 == v && i2 < i)) { v = v2; i = i2; }
        }
#pragma unroll
        for (int off = 1; off < 64; off <<= 1) {
            const float v2 = __shfl_xor(v, off, 64);
            const int i2 = __shfl_xor(i, off, 64);
            if (v2 > v || (v2 == v && i2 < i)) { v = v2; i = i2; }
        }
        if (t == 0) s_ct = i;
    }
    __syncthreads();
    const int ct = s_ct;
    const float cty = (float)(ct / FT);
    const float ctx = (float)(ct % FT);

    // ---- hps @ ct (weights from LDS) ----
    if (t < CIN) {
        const int cpy = ct / FT, cpx = ct % FT;
        float acc = s2_dwb[0][t];
#pragma unroll
        for (int ky = 0; ky < 3; ++ky) {
            const int yy = cpy + ky - 1;
#pragma unroll
            for (int kx = 0; kx < 3; ++kx) {
                const int xx = cpx + kx - 1;
                float v = 0.0f;
                if (yy >= 0 && yy < FT && xx >= 0 && xx < FT)
                    v = p.x[t * NPIX + yy * FT + xx] * NORM_SCALE - 1.0f;
                acc = fmaf(s2_dww[0][t * 9 + ky * 3 + kx], v, acc);
            }
        }
        s_dwv[t] = acc;
    }
    __syncthreads();
    if (t < HC) {
        float a = s2_pw1b[0][t];
#pragma unroll
        for (int ci = 0; ci < CIN; ++ci)
            a = fmaf(s2_pw1[0][t * CIN + ci], s_dwv[ci], a);
        sA[t] = fmaxf(a, 0.0f);
    }
    __syncthreads();
    if (t < 64) {
        float vy = 0.0f, vx = 0.0f;
        for (int co = t; co < HC; co += 64) {
            const float av = sA[co];
            vy = fmaf(s2_pw2[0][co], av, vy);
            vx = fmaf(s2_pw2[0][HC + co], av, vx);
        }
#pragma unroll
        for (int off = 1; off < 64; off <<= 1) {
            vy += __shfl_xor(vy, off, 64);
            vx += __shfl_xor(vx, off, 64);
        }
        if (t == 0) {
            s_ky = vy + s2_pw2b[0][0] + cty;
            s_kx = vx + s2_pw2b[0][1] + ctx;
        }
    }
    __syncthreads();
    const float kcy = s_ky, kcx = s_kx;

    // ---- distance-weighted argmax over prefetched heatmap row ----
    float best = -1e30f;
    int bi = 0x7fffffff;
#pragma unroll
    for (int j = 0; j < 9; ++j) {
        const int i = 256 * j + t;
        const int y = i / FT, xx = i % FT;
        const float dy = (float)y - kcy, dx = (float)xx - kcx;
        const float d = sqrtf(dy * dy + dx * dx) + DELTA;
        const float v = r[j] / d;
        if (v > best || (v == best && i < bi)) { best = v; bi = i; }
    }
    s_red[t] = best;
    s_redi[t] = bi;
    __syncthreads();
    for (int s = 128; s > 0; s >>= 1) {
        if (t < s) {
            const float v2 = s_red[t + s];
            const int i2 = s_redi[t + s];
            if (v2 > s_red[t] || (v2 == s_red[t] && i2 < s_redi[t])) {
                s_red[t] = v2;
                s_redi[t] = i2;
            }
        }
        __syncthreads();
    }
    if (t == 0) s_top = s_redi[0];
    __syncthreads();
    const int top = s_top;

    // ---- hp_offset @ top (weights from LDS) ----
    if (t < CIN) {
        const int tpy = top / FT, tpx = top % FT;
        float acc = s2_dwb[1][t];
#pragma unroll
        for (int ky = 0; ky < 3; ++ky) {
            const int yy = tpy + ky - 1;
#pragma unroll
            for (int kx = 0; kx < 3; ++kx) {
                const int xx = tpx + kx - 1;
                float v = 0.0f;
                if (yy >= 0 && yy < FT && xx >= 0 && xx < FT)
                    v = p.x[t * NPIX + yy * FT + xx] * NORM_SCALE - 1.0f;
                acc = fmaf(s2_dww[1][t * 9 + ky * 3 + kx], v, acc);
            }
        }
        s_dwv[t] = acc;
    }
    __syncthreads();
    if (t < HC) {
        float a = s2_pw1b[1][t];
#pragma unroll
        for (int ci = 0; ci < CIN; ++ci)
            a = fmaf(s2_pw1[1][t * CIN + ci], s_dwv[ci], a);
        sA[t] = fmaxf(a, 0.0f);
    }
    __syncthreads();
    if (t < 64) {
        float oy = 0.0f, ox = 0.0f;
        for (int co = t; co < HC; co += 64) {
            const float av = sA[co];
            oy = fmaf(s2_pw2[1][co], av, oy);
            ox = fmaf(s2_pw2[1][HC + co], av, ox);
        }
#pragma unroll
        for (int off = 1; off < 64; off <<= 1) {
            oy += __shfl_xor(oy, off, 64);
            ox += __shfl_xor(ox, off, 64);
        }
        if (t == 0) {
            const float ty = (float)(top / FT), tx = (float)(top % FT);
            p.out[k * 3 + 0] = (oy + s2_pw2b[1][0] + ty) * OUT_SCALE;
            p.out[k * 3 + 1] = (ox + s2_pw2b[1][1] + tx) * OUT_SCALE;
            p.out[k * 3 + 2] = p.hmhp_sig[k * NPIX + top];
        }
    }

    // ---- self-reset sync state for the next call ----
    __syncthreads();
    if (t == 0) {
        const int d = atomicAdd(&g_done, 1);
        if (d == NDEC - 1) {
            __hip_atomic_store(&g_done, 0, __ATOMIC_RELAXED, __HIP_MEMORY_SCOPE_AGENT);
            __hip_atomic_store(&g_counter, 0, __ATOMIC_RELEASE, __HIP_MEMORY_SCOPE_AGENT);
        }
    }
}

// ---------------- launch ----------------

extern "C" void kernel_launch(void* const* d_in, const int* in_sizes, int n_in,
                              void* d_out, int out_size, void* d_ws, size_t ws_size,
                              hipStream_t stream)
{
    (void)in_sizes; (void)n_in; (void)out_size; (void)ws_size;

    float* ws = (float*)d_ws;
    float* hmhp_sig = ws;                          // 17*2304 floats
    float* pval     = ws + 17 * NPIX;              // 72 floats
    int*   pidx     = (int*)(ws + 17 * NPIX + 72); // 72 ints

    PF p;
    p.x = (const float*)d_in[0];
    for (int h = 0; h < 4; ++h)
        for (int j = 0; j < 6; ++j)
            p.w[h][j] = (const float*)d_in[1 + h * 6 + j];
    p.hmhp_sig = hmhp_sig;
    p.pval = pval;
    p.pidx = pidx;
    p.out = (float*)d_out;

    fused<<<NPROD, 256, 0, stream>>>(p);
}

// Round 6
// 130.602 us; speedup vs baseline: 1.0439x; 1.0133x over previous
//
#include <hip/hip_runtime.h>
#include <math.h>

#define FT 48
#define NPIX 2304
#define CIN 24
#define HC 96
#define NORM_SCALE 0.007843137718737125f
#define OUT_SCALE 0.02083333395421505f
#define DELTA 1.8f

__device__ __forceinline__ float sigmoidf_(float v) { return 1.0f / (1.0f + expf(-v)); }

// ============================================================================
// kernel 1: 144 blocks x 256 threads.
//   blocks 0..71 : hm_hp head (17 ch), 32 pixels/block, 8 lanes coop per pixel
//   blocks 72..143: hm head (1 ch) + center-weighted partial argmax
// ============================================================================

struct P1 {
    const float* x;
    const float* hmhp_w[6];   // dw_w, dw_b, pw1_w, pw1_b, pw2_w, pw2_b
    const float* hm_w[6];
    float* hmhp_sig;          // [17][2304] sigmoided
    float* pval;              // [72]
    int*   pidx;              // [72]
};

__global__ __launch_bounds__(256) void k1_heads(P1 p)
{
    __shared__ float s_dww[216];
    __shared__ float s_dwb[24];
    __shared__ float s_pw1w[HC * CIN];    // [co][ci], row = 96 B (16B aligned)
    __shared__ float s_pw1b[HC];
    __shared__ float s_pw2t[HC * 20];     // [co][k] padded to stride 20 (80 B, 16B aligned)
    __shared__ float s_pw2b[17];
    __shared__ float sv[4];
    __shared__ int si[4];

    const int t = threadIdx.x;
    const int b = blockIdx.x;
    const bool is_hm = (b >= 72);
    const int lb = is_hm ? b - 72 : b;

    const float* dw_w  = is_hm ? p.hm_w[0] : p.hmhp_w[0];
    const float* dw_b  = is_hm ? p.hm_w[1] : p.hmhp_w[1];
    const float* pw1_w = is_hm ? p.hm_w[2] : p.hmhp_w[2];
    const float* pw1_b = is_hm ? p.hm_w[3] : p.hmhp_w[3];
    const float* pw2_w = is_hm ? p.hm_w[4] : p.hmhp_w[4];
    const float* pw2_b = is_hm ? p.hm_w[5] : p.hmhp_w[5];

    // ---- stage weights -> LDS (cold HBM; overlapped with x tap loads below) ----
    if (t < 216) s_dww[t] = dw_w[t];
    if (t < 24) s_dwb[t] = dw_b[t];
    for (int i = t; i < HC * CIN; i += 256) s_pw1w[i] = pw1_w[i];
    if (t < HC) s_pw1b[t] = pw1_b[t];
    if (!is_hm) {
        for (int i = t; i < HC * 17; i += 256) {
            const int co = i / 17, k = i - co * 17;
            s_pw2t[co * 20 + k] = pw2_w[k * HC + co];
        }
        if (t < 17) s_pw2b[t] = pw2_b[t];
    } else {
        if (t < HC) s_pw2t[t * 20] = pw2_w[t];
        if (t == 0) s_pw2b[0] = pw2_b[0];
    }

    // ---- producer layout: 32 pixels/block, 8 lanes cooperate per pixel ----
    const int lane = t & 63;
    const int split = lane & 7;
    const int pix = lb * 32 + (t >> 3);
    const int py = pix / FT;
    const int px = pix % FT;

    // prefetch this lane's 27 normalized x-taps into regs before the barrier
    float xt[3][9];
#pragma unroll
    for (int c = 0; c < 3; ++c) {
        const int ci = split * 3 + c;
#pragma unroll
        for (int ky = 0; ky < 3; ++ky) {
            const int yy = py + ky - 1;
#pragma unroll
            for (int kx = 0; kx < 3; ++kx) {
                const int xx = px + kx - 1;
                float v = 0.0f;
                if (yy >= 0 && yy < FT && xx >= 0 && xx < FT)
                    v = p.x[ci * NPIX + yy * FT + xx] * NORM_SCALE - 1.0f;
                xt[c][ky * 3 + kx] = v;
            }
        }
    }
    __syncthreads();

    // depthwise: lane computes dw channels 3*split..3*split+2
    float part[3];
#pragma unroll
    for (int c = 0; c < 3; ++c) {
        const int ci = split * 3 + c;
        float acc = s_dwb[ci];
#pragma unroll
        for (int tap = 0; tap < 9; ++tap)
            acc = fmaf(s_dww[ci * 9 + tap], xt[c][tap], acc);
        part[c] = acc;
    }

    // share dwv[24] within the 8-lane group
    float dwv[CIN];
    const int gbase = lane & ~7;
#pragma unroll
    for (int ci = 0; ci < CIN; ++ci) {
        const float v = (ci % 3 == 0) ? part[0] : ((ci % 3 == 1) ? part[1] : part[2]);
        dwv[ci] = __shfl(v, gbase | (ci / 3), 64);
    }

    if (!is_hm) {
        float oacc[17];
#pragma unroll
        for (int k = 0; k < 17; ++k) oacc[k] = 0.0f;
#pragma unroll
        for (int j = 0; j < 12; ++j) {
            const int co = j * 8 + split;
            const float4* w4 = (const float4*)&s_pw1w[co * CIN];
            float a = s_pw1b[co];
#pragma unroll
            for (int q = 0; q < 6; ++q) {
                const float4 wv = w4[q];
                a = fmaf(wv.x, dwv[4 * q + 0], a);
                a = fmaf(wv.y, dwv[4 * q + 1], a);
                a = fmaf(wv.z, dwv[4 * q + 2], a);
                a = fmaf(wv.w, dwv[4 * q + 3], a);
            }
            a = fmaxf(a, 0.0f);
            const float4* q4 = (const float4*)&s_pw2t[co * 20];
#pragma unroll
            for (int q = 0; q < 4; ++q) {
                const float4 qq = q4[q];
                oacc[4 * q + 0] = fmaf(qq.x, a, oacc[4 * q + 0]);
                oacc[4 * q + 1] = fmaf(qq.y, a, oacc[4 * q + 1]);
                oacc[4 * q + 2] = fmaf(qq.z, a, oacc[4 * q + 2]);
                oacc[4 * q + 3] = fmaf(qq.w, a, oacc[4 * q + 3]);
            }
            oacc[16] = fmaf(s_pw2t[co * 20 + 16], a, oacc[16]);
        }
#pragma unroll
        for (int off = 1; off < 8; off <<= 1)
#pragma unroll
            for (int k = 0; k < 17; ++k)
                oacc[k] += __shfl_xor(oacc[k], off, 64);
        {
            int k = split;
            p.hmhp_sig[k * NPIX + pix] = sigmoidf_(oacc[k] + s_pw2b[k]);
            k = split + 8;
            p.hmhp_sig[k * NPIX + pix] = sigmoidf_(oacc[k] + s_pw2b[k]);
            if (split == 0)
                p.hmhp_sig[16 * NPIX + pix] = sigmoidf_(oacc[16] + s_pw2b[16]);
        }
    } else {
        float acc1 = 0.0f;
#pragma unroll
        for (int j = 0; j < 12; ++j) {
            const int co = j * 8 + split;
            const float4* w4 = (const float4*)&s_pw1w[co * CIN];
            float a = s_pw1b[co];
#pragma unroll
            for (int q = 0; q < 6; ++q) {
                const float4 wv = w4[q];
                a = fmaf(wv.x, dwv[4 * q + 0], a);
                a = fmaf(wv.y, dwv[4 * q + 1], a);
                a = fmaf(wv.z, dwv[4 * q + 2], a);
                a = fmaf(wv.w, dwv[4 * q + 3], a);
            }
            a = fmaxf(a, 0.0f);
            acc1 = fmaf(s_pw2t[co * 20], a, acc1);
        }
#pragma unroll
        for (int off = 1; off < 8; off <<= 1)
            acc1 += __shfl_xor(acc1, off, 64);

        float v = -1e30f;
        int idx = pix;
        if (split == 0) {
            const float o = acc1 + s_pw2b[0];
            const float gy = (float)py - 24.0f, gx = (float)px - 24.0f;
            const float w = 1.0f / (sqrtf(gy * gy + gx * gx) + DELTA);
            v = sigmoidf_(o) * w;
        }
#pragma unroll
        for (int off = 1; off < 64; off <<= 1) {
            const float v2 = __shfl_xor(v, off, 64);
            const int i2 = __shfl_xor(idx, off, 64);
            if (v2 > v || (v2 == v && i2 < idx)) { v = v2; idx = i2; }
        }
        if (lane == 0) { sv[t >> 6] = v; si[t >> 6] = idx; }
        __syncthreads();
        if (t == 0) {
            float bv = sv[0]; int bi = si[0];
#pragma unroll
            for (int w2 = 1; w2 < 4; ++w2)
                if (sv[w2] > bv || (sv[w2] == bv && si[w2] < bi)) { bv = sv[w2]; bi = si[w2]; }
            p.pval[lb] = bv;
            p.pidx[lb] = bi;
        }
    }
}

// ============================================================================
// kernel 2: 17 blocks x 256 threads, one block per keypoint.
// ============================================================================

struct P2 {
    const float* x;
    const float* hps_w[6];
    const float* hpo_w[6];
    const float* hmhp_sig;
    const float* pval;
    const int*   pidx;
    float* out;
};

__global__ __launch_bounds__(256) void k2_decode(P2 p)
{
    __shared__ float s2_dww[2][216];      // 0=hps, 1=hp_offset
    __shared__ float s2_dwb[2][24];
    __shared__ float s2_pw1[2][HC * CIN];
    __shared__ float s2_pw1b[2][HC];
    __shared__ float s2_pw2[2][2 * HC];   // rows 2k and 2k+1
    __shared__ float s2_pw2b[2][2];
    __shared__ float s_red[4];
    __shared__ int s_redi[4];
    __shared__ float s_dwv[CIN];
    __shared__ float sA[HC];
    __shared__ float s_ky, s_kx;
    __shared__ int s_ct, s_top;

    const int t = threadIdx.x;
    const int k = blockIdx.x;
    const int lane = t & 63;
    const int wv = t >> 6;

    // ---- issue ALL independent cold loads up front ----
    // heatmap row -> regs
    float r[9];
#pragma unroll
    for (int j = 0; j < 9; ++j)
        r[j] = p.hmhp_sig[k * NPIX + 256 * j + t];
    // weight staging -> LDS
    for (int i = t; i < HC * CIN; i += 256) {
        s2_pw1[0][i] = p.hps_w[2][i];
        s2_pw1[1][i] = p.hpo_w[2][i];
    }
    if (t < HC) {
        s2_pw1b[0][t] = p.hps_w[3][t];
        s2_pw1b[1][t] = p.hpo_w[3][t];
        s2_pw2[0][t]      = p.hps_w[4][(2 * k) * HC + t];
        s2_pw2[0][HC + t] = p.hps_w[4][(2 * k + 1) * HC + t];
        s2_pw2[1][t]      = p.hpo_w[4][(2 * k) * HC + t];
        s2_pw2[1][HC + t] = p.hpo_w[4][(2 * k + 1) * HC + t];
    }
    if (t < 216) { s2_dww[0][t] = p.hps_w[0][t]; s2_dww[1][t] = p.hpo_w[0][t]; }
    if (t < 24)  { s2_dwb[0][t] = p.hps_w[1][t]; s2_dwb[1][t] = p.hpo_w[1][t]; }
    if (t < 2)   { s2_pw2b[0][t] = p.hps_w[5][2 * k + t]; s2_pw2b[1][t] = p.hpo_w[5][2 * k + t]; }

    // ---- center argmax finalize: wave-0 butterfly over 72 partials ----
    if (t < 64) {
        float v = p.pval[t];
        int i = p.pidx[t];
        if (t < 8) {
            const float v2 = p.pval[64 + t];
            const int i2 = p.pidx[64 + t];
            if (v2 > v || (v2 == v && i2 < i)) { v = v2; i = i2; }
        }
#pragma unroll
        for (int off = 1; off < 64; off <<= 1) {
            const float v2 = __shfl_xor(v, off, 64);
            const int i2 = __shfl_xor(i, off, 64);
            if (v2 > v || (v2 == v && i2 < i)) { v = v2; i = i2; }
        }
        if (t == 0) s_ct = i;
    }
    __syncthreads();
    const int ct = s_ct;
    const float cty = (float)(ct / FT);
    const float ctx = (float)(ct % FT);

    // ---- hps @ ct ----
    if (t < CIN) {
        const int cpy = ct / FT, cpx = ct % FT;
        float acc = s2_dwb[0][t];
#pragma unroll
        for (int ky = 0; ky < 3; ++ky) {
            const int yy = cpy + ky - 1;
#pragma unroll
            for (int kx = 0; kx < 3; ++kx) {
                const int xx = cpx + kx - 1;
                float v = 0.0f;
                if (yy >= 0 && yy < FT && xx >= 0 && xx < FT)
                    v = p.x[t * NPIX + yy * FT + xx] * NORM_SCALE - 1.0f;
                acc = fmaf(s2_dww[0][t * 9 + ky * 3 + kx], v, acc);
            }
        }
        s_dwv[t] = acc;
    }
    __syncthreads();
    if (t < HC) {
        float a = s2_pw1b[0][t];
#pragma unroll
        for (int ci = 0; ci < CIN; ++ci)
            a = fmaf(s2_pw1[0][t * CIN + ci], s_dwv[ci], a);
        sA[t] = fmaxf(a, 0.0f);
    }
    __syncthreads();
    if (t < 64) {
        float vy = 0.0f, vx = 0.0f;
        for (int co = t; co < HC; co += 64) {
            const float av = sA[co];
            vy = fmaf(s2_pw2[0][co], av, vy);
            vx = fmaf(s2_pw2[0][HC + co], av, vx);
        }
#pragma unroll
        for (int off = 1; off < 64; off <<= 1) {
            vy += __shfl_xor(vy, off, 64);
            vx += __shfl_xor(vx, off, 64);
        }
        if (t == 0) {
            s_ky = vy + s2_pw2b[0][0] + cty;
            s_kx = vx + s2_pw2b[0][1] + ctx;
        }
    }
    __syncthreads();
    const float kcy = s_ky, kcx = s_kx;

    // ---- distance-weighted argmax over the prefetched heatmap row ----
    float best = -1e30f;
    int bi = 0x7fffffff;
#pragma unroll
    for (int j = 0; j < 9; ++j) {
        const int i = 256 * j + t;
        const int y = i / FT, xx = i % FT;
        const float dy = (float)y - kcy, dx = (float)xx - kcx;
        const float d = sqrtf(dy * dy + dx * dx) + DELTA;
        const float v = r[j] / d;
        if (v > best || (v == best && i < bi)) { best = v; bi = i; }
    }
#pragma unroll
    for (int off = 1; off < 64; off <<= 1) {
        const float v2 = __shfl_xor(best, off, 64);
        const int i2 = __shfl_xor(bi, off, 64);
        if (v2 > best || (v2 == best && i2 < bi)) { best = v2; bi = i2; }
    }
    if (lane == 0) { s_red[wv] = best; s_redi[wv] = bi; }
    __syncthreads();
    if (t == 0) {
        float bv = s_red[0]; int bb = s_redi[0];
#pragma unroll
        for (int w2 = 1; w2 < 4; ++w2)
            if (s_red[w2] > bv || (s_red[w2] == bv && s_redi[w2] < bb)) { bv = s_red[w2]; bb = s_redi[w2]; }
        s_top = bb;
    }
    __syncthreads();
    const int top = s_top;

    // ---- hp_offset @ top ----
    if (t < CIN) {
        const int tpy = top / FT, tpx = top % FT;
        float acc = s2_dwb[1][t];
#pragma unroll
        for (int ky = 0; ky < 3; ++ky) {
            const int yy = tpy + ky - 1;
#pragma unroll
            for (int kx = 0; kx < 3; ++kx) {
                const int xx = tpx + kx - 1;
                float v = 0.0f;
                if (yy >= 0 && yy < FT && xx >= 0 && xx < FT)
                    v = p.x[t * NPIX + yy * FT + xx] * NORM_SCALE - 1.0f;
                acc = fmaf(s2_dww[1][t * 9 + ky * 3 + kx], v, acc);
            }
        }
        s_dwv[t] = acc;
    }
    __syncthreads();
    if (t < HC) {
        float a = s2_pw1b[1][t];
#pragma unroll
        for (int ci = 0; ci < CIN; ++ci)
            a = fmaf(s2_pw1[1][t * CIN + ci], s_dwv[ci], a);
        sA[t] = fmaxf(a, 0.0f);
    }
    __syncthreads();
    if (t < 64) {
        float oy = 0.0f, ox = 0.0f;
        for (int co = t; co < HC; co += 64) {
            const float av = sA[co];
            oy = fmaf(s2_pw2[1][co], av, oy);
            ox = fmaf(s2_pw2[1][HC + co], av, ox);
        }
#pragma unroll
        for (int off = 1; off < 64; off <<= 1) {
            oy += __shfl_xor(oy, off, 64);
            ox += __shfl_xor(ox, off, 64);
        }
        if (t == 0) {
            const float ty = (float)(top / FT), tx = (float)(top % FT);
            p.out[k * 3 + 0] = (oy + s2_pw2b[1][0] + ty) * OUT_SCALE;
            p.out[k * 3 + 1] = (ox + s2_pw2b[1][1] + tx) * OUT_SCALE;
            p.out[k * 3 + 2] = p.hmhp_sig[k * NPIX + top];
        }
    }
}

// ---------------- launch ----------------

extern "C" void kernel_launch(void* const* d_in, const int* in_sizes, int n_in,
                              void* d_out, int out_size, void* d_ws, size_t ws_size,
                              hipStream_t stream)
{
    (void)in_sizes; (void)n_in; (void)out_size; (void)ws_size;

    float* ws = (float*)d_ws;
    float* hmhp_sig = ws;                          // 17*2304 floats
    float* pval     = ws + 17 * NPIX;              // 72 floats
    int*   pidx     = (int*)(ws + 17 * NPIX + 72); // 72 ints

    P1 p1;
    p1.x = (const float*)d_in[0];
    for (int j = 0; j < 6; ++j) p1.hmhp_w[j] = (const float*)d_in[1 + j];
    for (int j = 0; j < 6; ++j) p1.hm_w[j]   = (const float*)d_in[7 + j];
    p1.hmhp_sig = hmhp_sig;
    p1.pval = pval;
    p1.pidx = pidx;

    P2 p2;
    p2.x = (const float*)d_in[0];
    for (int j = 0; j < 6; ++j) p2.hps_w[j] = (const float*)d_in[13 + j];
    for (int j = 0; j < 6; ++j) p2.hpo_w[j] = (const float*)d_in[19 + j];
    p2.hmhp_sig = hmhp_sig;
    p2.pval = pval;
    p2.pidx = pidx;
    p2.out = (float*)d_out;

    k1_heads<<<144, 256, 0, stream>>>(p1);
    k2_decode<<<17, 256, 0, stream>>>(p2);
}

// Round 7
// 126.439 us; speedup vs baseline: 1.0783x; 1.0329x over previous
//
#include <hip/hip_runtime.h>
#include <math.h>

#define FT 48
#define NPIX 2304
#define CIN 24
#define HC 96
#define NORM_SCALE 0.007843137718737125f
#define OUT_SCALE 0.02083333395421505f
#define DELTA 1.8f

__device__ __forceinline__ float sigmoidf_(float v) { return 1.0f / (1.0f + expf(-v)); }

// ============================================================================
// kernel 1: 144 blocks x 256 threads, ONE unified compute path.
//   blocks 0..71 : hm_hp head (17 ch), 32 pixels/block, 8 lanes coop per pixel
//   blocks 72..143: hm head runs the same 17-wide path with pw2 zero-padded to
//                   column 0; tail does the center-weighted partial argmax.
// ============================================================================

struct P1 {
    const float* x;
    const float* hmhp_w[6];   // dw_w, dw_b, pw1_w, pw1_b, pw2_w, pw2_b
    const float* hm_w[6];
    float* hmhp_sig;          // [17][2304] sigmoided
    float* pval;              // [72]
    int*   pidx;              // [72]
};

__global__ __launch_bounds__(256) void k1_heads(P1 p)
{
    __shared__ float s_dww[216];
    __shared__ float s_dwb[24];
    __shared__ float s_pw1w[HC * CIN];    // [co][ci], row 96 B (16B aligned)
    __shared__ float s_pw1b[HC];
    __shared__ float s_pw2t[HC * 20];     // [co][k], stride 20 (80 B, 16B aligned)
    __shared__ float s_pw2b[17];
    __shared__ float sv[4];
    __shared__ int si[4];

    const int t = threadIdx.x;
    const int b = blockIdx.x;
    const bool is_hm = (b >= 72);
    const int lb = is_hm ? b - 72 : b;

    const float* dw_w  = is_hm ? p.hm_w[0] : p.hmhp_w[0];
    const float* dw_b  = is_hm ? p.hm_w[1] : p.hmhp_w[1];
    const float* pw1_w = is_hm ? p.hm_w[2] : p.hmhp_w[2];
    const float* pw1_b = is_hm ? p.hm_w[3] : p.hmhp_w[3];
    const float* pw2_w = is_hm ? p.hm_w[4] : p.hmhp_w[4];
    const float* pw2_b = is_hm ? p.hm_w[5] : p.hmhp_w[5];

    // ---- stage weights -> LDS ----
    if (t < 216) s_dww[t] = dw_w[t];
    if (t < 24) s_dwb[t] = dw_b[t];
    for (int i = t; i < HC * CIN; i += 256) s_pw1w[i] = pw1_w[i];
    if (t < HC) s_pw1b[t] = pw1_b[t];
    if (!is_hm) {
        for (int i = t; i < HC * 17; i += 256) {
            const int co = i / 17, k = i - co * 17;
            s_pw2t[co * 20 + k] = pw2_w[k * HC + co];
        }
        if (t < 17) s_pw2b[t] = pw2_b[t];
    } else {
        // zero-pad, then place hm's 96 pw2 weights in column 0
        for (int i = t; i < HC * 20; i += 256) s_pw2t[i] = 0.0f;
        if (t == 0) s_pw2b[0] = pw2_b[0];
    }

    // ---- layout: 32 pixels/block, 8 lanes cooperate per pixel ----
    const int lane = t & 63;
    const int split = lane & 7;
    const int pix = lb * 32 + (t >> 3);
    const int py = pix / FT;
    const int px = pix % FT;

    // prefetch this lane's 27 normalized x-taps into regs before the barrier
    float xt[3][9];
#pragma unroll
    for (int c = 0; c < 3; ++c) {
        const int ci = split * 3 + c;
#pragma unroll
        for (int ky = 0; ky < 3; ++ky) {
            const int yy = py + ky - 1;
#pragma unroll
            for (int kx = 0; kx < 3; ++kx) {
                const int xx = px + kx - 1;
                float v = 0.0f;
                if (yy >= 0 && yy < FT && xx >= 0 && xx < FT)
                    v = p.x[ci * NPIX + yy * FT + xx] * NORM_SCALE - 1.0f;
                xt[c][ky * 3 + kx] = v;
            }
        }
    }
    if (is_hm && t < HC) {
        // overwrite column 0 AFTER the zero-pad loop above (same thread set
        // touches disjoint LDS words, but order within this thread matters)
        s_pw2t[t * 20] = pw2_w[t];
    }
    __syncthreads();

    // depthwise: lane computes dw channels 3*split..3*split+2
    float part[3];
#pragma unroll
    for (int c = 0; c < 3; ++c) {
        const int ci = split * 3 + c;
        float acc = s_dwb[ci];
#pragma unroll
        for (int tap = 0; tap < 9; ++tap)
            acc = fmaf(s_dww[ci * 9 + tap], xt[c][tap], acc);
        part[c] = acc;
    }

    // share dwv[24] within the 8-lane group
    float dwv[CIN];
    const int gbase = lane & ~7;
#pragma unroll
    for (int ci = 0; ci < CIN; ++ci) {
        const float v = (ci % 3 == 0) ? part[0] : ((ci % 3 == 1) ? part[1] : part[2]);
        dwv[ci] = __shfl(v, gbase | (ci / 3), 64);
    }

    // ---- unified pw1+pw2 accumulation (17-wide for every block) ----
    float oacc[17];
#pragma unroll
    for (int k = 0; k < 17; ++k) oacc[k] = 0.0f;
#pragma unroll 2
    for (int j = 0; j < 12; ++j) {
        const int co = j * 8 + split;
        const float4* w4 = (const float4*)&s_pw1w[co * CIN];
        float a = s_pw1b[co];
#pragma unroll
        for (int q = 0; q < 6; ++q) {
            const float4 wv = w4[q];
            a = fmaf(wv.x, dwv[4 * q + 0], a);
            a = fmaf(wv.y, dwv[4 * q + 1], a);
            a = fmaf(wv.z, dwv[4 * q + 2], a);
            a = fmaf(wv.w, dwv[4 * q + 3], a);
        }
        a = fmaxf(a, 0.0f);
        const float4* q4 = (const float4*)&s_pw2t[co * 20];
#pragma unroll
        for (int q = 0; q < 4; ++q) {
            const float4 qq = q4[q];
            oacc[4 * q + 0] = fmaf(qq.x, a, oacc[4 * q + 0]);
            oacc[4 * q + 1] = fmaf(qq.y, a, oacc[4 * q + 1]);
            oacc[4 * q + 2] = fmaf(qq.z, a, oacc[4 * q + 2]);
            oacc[4 * q + 3] = fmaf(qq.w, a, oacc[4 * q + 3]);
        }
        oacc[16] = fmaf(s_pw2t[co * 20 + 16], a, oacc[16]);
    }
    // reduce across the 8 splits
#pragma unroll
    for (int off = 1; off < 8; off <<= 1)
#pragma unroll
        for (int k = 0; k < 17; ++k)
            oacc[k] += __shfl_xor(oacc[k], off, 64);

    if (!is_hm) {
        int k = split;
        p.hmhp_sig[k * NPIX + pix] = sigmoidf_(oacc[k] + s_pw2b[k]);
        k = split + 8;
        p.hmhp_sig[k * NPIX + pix] = sigmoidf_(oacc[k] + s_pw2b[k]);
        if (split == 0)
            p.hmhp_sig[16 * NPIX + pix] = sigmoidf_(oacc[16] + s_pw2b[16]);
    } else {
        float v = -1e30f;
        int idx = pix;
        if (split == 0) {
            const float o = oacc[0] + s_pw2b[0];
            const float gy = (float)py - 24.0f, gx = (float)px - 24.0f;
            const float w = 1.0f / (sqrtf(gy * gy + gx * gx) + DELTA);
            v = sigmoidf_(o) * w;
        }
#pragma unroll
        for (int off = 1; off < 64; off <<= 1) {
            const float v2 = __shfl_xor(v, off, 64);
            const int i2 = __shfl_xor(idx, off, 64);
            if (v2 > v || (v2 == v && i2 < idx)) { v = v2; idx = i2; }
        }
        if (lane == 0) { sv[t >> 6] = v; si[t >> 6] = idx; }
        __syncthreads();
        if (t == 0) {
            float bv = sv[0]; int bi = si[0];
#pragma unroll
            for (int w2 = 1; w2 < 4; ++w2)
                if (sv[w2] > bv || (sv[w2] == bv && si[w2] < bi)) { bv = sv[w2]; bi = si[w2]; }
            p.pval[lb] = bv;
            p.pidx[lb] = bi;
        }
    }
}

// ============================================================================
// kernel 2: 17 blocks x 256 threads, one block per keypoint.
// Single h-loop runs the {hps@ct, hp_offset@top} matvec pipeline twice.
// ============================================================================

struct P2 {
    const float* x;
    const float* hps_w[6];
    const float* hpo_w[6];
    const float* hmhp_sig;
    const float* pval;
    const int*   pidx;
    float* out;
};

__global__ __launch_bounds__(256) void k2_decode(P2 p)
{
    __shared__ float s2_dww[2][216];      // 0=hps, 1=hp_offset
    __shared__ float s2_dwb[2][24];
    __shared__ float s2_pw1[2][HC * CIN];
    __shared__ float s2_pw1b[2][HC];
    __shared__ float s2_pw2[2][2 * HC];   // rows 2k and 2k+1
    __shared__ float s2_pw2b[2][2];
    __shared__ float s_red[4];
    __shared__ int s_redi[4];
    __shared__ float s_dwv[CIN];
    __shared__ float sA[HC];
    __shared__ float s_ky, s_kx;
    __shared__ int s_ct, s_top;

    const int t = threadIdx.x;
    const int k = blockIdx.x;
    const int lane = t & 63;
    const int wv = t >> 6;

    // ---- issue ALL independent cold loads up front ----
    float r[9];
#pragma unroll
    for (int j = 0; j < 9; ++j)
        r[j] = p.hmhp_sig[k * NPIX + 256 * j + t];
    for (int i = t; i < HC * CIN; i += 256) {
        s2_pw1[0][i] = p.hps_w[2][i];
        s2_pw1[1][i] = p.hpo_w[2][i];
    }
    if (t < HC) {
        s2_pw1b[0][t] = p.hps_w[3][t];
        s2_pw1b[1][t] = p.hpo_w[3][t];
        s2_pw2[0][t]      = p.hps_w[4][(2 * k) * HC + t];
        s2_pw2[0][HC + t] = p.hps_w[4][(2 * k + 1) * HC + t];
        s2_pw2[1][t]      = p.hpo_w[4][(2 * k) * HC + t];
        s2_pw2[1][HC + t] = p.hpo_w[4][(2 * k + 1) * HC + t];
    }
    if (t < 216) { s2_dww[0][t] = p.hps_w[0][t]; s2_dww[1][t] = p.hpo_w[0][t]; }
    if (t < 24)  { s2_dwb[0][t] = p.hps_w[1][t]; s2_dwb[1][t] = p.hpo_w[1][t]; }
    if (t < 2)   { s2_pw2b[0][t] = p.hps_w[5][2 * k + t]; s2_pw2b[1][t] = p.hpo_w[5][2 * k + t]; }

    // ---- center argmax finalize: wave-0 butterfly over 72 partials ----
    if (t < 64) {
        float v = p.pval[t];
        int i = p.pidx[t];
        if (t < 8) {
            const float v2 = p.pval[64 + t];
            const int i2 = p.pidx[64 + t];
            if (v2 > v || (v2 == v && i2 < i)) { v = v2; i = i2; }
        }
#pragma unroll
        for (int off = 1; off < 64; off <<= 1) {
            const float v2 = __shfl_xor(v, off, 64);
            const int i2 = __shfl_xor(i, off, 64);
            if (v2 > v || (v2 == v && i2 < i)) { v = v2; i = i2; }
        }
        if (t == 0) s_ct = i;
    }
    __syncthreads();
    const int ct = s_ct;
    const float cty = (float)(ct / FT);
    const float ctx = (float)(ct % FT);

    for (int h = 0; h < 2; ++h) {
        const int pixel = (h == 0) ? ct : s_top;

        // dwconv at 'pixel' (24 threads, one channel each)
        if (t < CIN) {
            const int pyy = pixel / FT, pxx = pixel % FT;
            float acc = s2_dwb[h][t];
#pragma unroll
            for (int ky = 0; ky < 3; ++ky) {
                const int yy = pyy + ky - 1;
#pragma unroll
                for (int kx = 0; kx < 3; ++kx) {
                    const int xx = pxx + kx - 1;
                    float v = 0.0f;
                    if (yy >= 0 && yy < FT && xx >= 0 && xx < FT)
                        v = p.x[t * NPIX + yy * FT + xx] * NORM_SCALE - 1.0f;
                    acc = fmaf(s2_dww[h][t * 9 + ky * 3 + kx], v, acc);
                }
            }
            s_dwv[t] = acc;
        }
        __syncthreads();

        // pw1 + relu (96 threads)
        if (t < HC) {
            const float4* w4 = (const float4*)&s2_pw1[h][t * CIN];
            float a = s2_pw1b[h][t];
#pragma unroll
            for (int q = 0; q < 6; ++q) {
                const float4 wvv = w4[q];
                a = fmaf(wvv.x, s_dwv[4 * q + 0], a);
                a = fmaf(wvv.y, s_dwv[4 * q + 1], a);
                a = fmaf(wvv.z, s_dwv[4 * q + 2], a);
                a = fmaf(wvv.w, s_dwv[4 * q + 3], a);
            }
            sA[t] = fmaxf(a, 0.0f);
        }
        __syncthreads();

        // two pw2 dots (rows 2k, 2k+1), wave-0 butterfly
        if (t < 64) {
            float vy = 0.0f, vx = 0.0f;
            for (int co = t; co < HC; co += 64) {
                const float av = sA[co];
                vy = fmaf(s2_pw2[h][co], av, vy);
                vx = fmaf(s2_pw2[h][HC + co], av, vx);
            }
#pragma unroll
            for (int off = 1; off < 64; off <<= 1) {
                vy += __shfl_xor(vy, off, 64);
                vx += __shfl_xor(vx, off, 64);
            }
            if (t == 0) {
                if (h == 0) {
                    s_ky = vy + s2_pw2b[0][0] + cty;
                    s_kx = vx + s2_pw2b[0][1] + ctx;
                } else {
                    const int top = pixel;
                    const float ty = (float)(top / FT), tx = (float)(top % FT);
                    p.out[k * 3 + 0] = (vy + s2_pw2b[1][0] + ty) * OUT_SCALE;
                    p.out[k * 3 + 1] = (vx + s2_pw2b[1][1] + tx) * OUT_SCALE;
                    p.out[k * 3 + 2] = p.hmhp_sig[k * NPIX + top];
                }
            }
        }
        __syncthreads();

        if (h == 0) {
            // distance-weighted argmax over the prefetched heatmap row
            const float kcy = s_ky, kcx = s_kx;
            float best = -1e30f;
            int bi = 0x7fffffff;
#pragma unroll
            for (int j = 0; j < 9; ++j) {
                const int i = 256 * j + t;
                const int y = i / FT, xx = i % FT;
                const float dy = (float)y - kcy, dx = (float)xx - kcx;
                const float d = sqrtf(dy * dy + dx * dx) + DELTA;
                const float v = r[j] / d;
                if (v > best || (v == best && i < bi)) { best = v; bi = i; }
            }
#pragma unroll
            for (int off = 1; off < 64; off <<= 1) {
                const float v2 = __shfl_xor(best, off, 64);
                const int i2 = __shfl_xor(bi, off, 64);
                if (v2 > best || (v2 == best && i2 < bi)) { best = v2; bi = i2; }
            }
            if (lane == 0) { s_red[wv] = best; s_redi[wv] = bi; }
            __syncthreads();
            if (t == 0) {
                float bv = s_red[0]; int bb = s_redi[0];
#pragma unroll
                for (int w2 = 1; w2 < 4; ++w2)
                    if (s_red[w2] > bv || (s_red[w2] == bv && s_redi[w2] < bb)) { bv = s_red[w2]; bb = s_redi[w2]; }
                s_top = bb;
            }
            __syncthreads();
        }
    }
}

// ---------------- launch ----------------

extern "C" void kernel_launch(void* const* d_in, const int* in_sizes, int n_in,
                              void* d_out, int out_size, void* d_ws, size_t ws_size,
                              hipStream_t stream)
{
    (void)in_sizes; (void)n_in; (void)out_size; (void)ws_size;

    float* ws = (float*)d_ws;
    float* hmhp_sig = ws;                          // 17*2304 floats
    float* pval     = ws + 17 * NPIX;              // 72 floats
    int*   pidx     = (int*)(ws + 17 * NPIX + 72); // 72 ints

    P1 p1;
    p1.x = (const float*)d_in[0];
    for (int j = 0; j < 6; ++j) p1.hmhp_w[j] = (const float*)d_in[1 + j];
    for (int j = 0; j < 6; ++j) p1.hm_w[j]   = (const float*)d_in[7 + j];
    p1.hmhp_sig = hmhp_sig;
    p1.pval = pval;
    p1.pidx = pidx;

    P2 p2;
    p2.x = (const float*)d_in[0];
    for (int j = 0; j < 6; ++j) p2.hps_w[j] = (const float*)d_in[13 + j];
    for (int j = 0; j < 6; ++j) p2.hpo_w[j] = (const float*)d_in[19 + j];
    p2.hmhp_sig = hmhp_sig;
    p2.pval = pval;
    p2.pidx = pidx;
    p2.out = (float*)d_out;

    k1_heads<<<144, 256, 0, stream>>>(p1);
    k2_decode<<<17, 256, 0, stream>>>(p2);
}